// Round 15
// baseline (145.019 us; speedup 1.0000x reference)
//
#include <hip/hip_runtime.h>
#include <hip/hip_bf16.h>

#define BB 32
#define TT 512
#define IND 16
#define FD 128
#define NAGG 32

typedef unsigned short ushortt;
typedef unsigned int uintt;
typedef __attribute__((ext_vector_type(8))) short bf16x8;
typedef __attribute__((ext_vector_type(4))) short s16x4;
typedef __attribute__((ext_vector_type(4))) float f32x4;

__device__ __forceinline__ short f2b(float x) {
  union { __hip_bfloat16 h; short s; } u;
  u.h = __float2bfloat16(x);
  return u.s;
}

#define MFMA_16x16x32(A, B, C) __builtin_amdgcn_mfma_f32_16x16x32_bf16(A, B, C, 0, 0, 0)

// K=128 GEMM over 32-row LDS tile Xb, cols c0/c1 per wave, frags per m89 mapping.
#define GEMM128(WT, c00, c01, c10, c11)                                        \
  {                                                                            \
    _Pragma("unroll") for (int ks = 0; ks < 4; ks++) {                         \
      bf16x8 a0 = *(const bf16x8*)&Xb[l15][ks * 32 + g * 8];                   \
      bf16x8 a1 = *(const bf16x8*)&Xb[16 + l15][ks * 32 + g * 8];              \
      bf16x8 b0 = *(const bf16x8*)((WT) + (size_t)c0 * 128 + ks * 32 + g * 8); \
      bf16x8 b1 = *(const bf16x8*)((WT) + (size_t)c1 * 128 + ks * 32 + g * 8); \
      c00 = MFMA_16x16x32(a0, b0, c00);                                        \
      c01 = MFMA_16x16x32(a0, b1, c01);                                        \
      c10 = MFMA_16x16x32(a1, b0, c10);                                        \
      c11 = MFMA_16x16x32(a1, b1, c11);                                        \
    }                                                                          \
  }

// ---- prep: transpose weights to bf16 W^T. grid 8*4, 256 thr ----
__global__ void prep_w_k(const float* __restrict__ wo0, const float* __restrict__ wq1,
                         const float* __restrict__ wk1, const float* __restrict__ wv1,
                         const float* __restrict__ wo1, const float* __restrict__ wti,
                         const float* __restrict__ wto, const float* __restrict__ was,
                         ushortt* __restrict__ Wt) {
  int m = blockIdx.x >> 2;
  int slab = blockIdx.x & 3;
  int tid = threadIdx.x;
  if (m == 7) {  // wast[32][128] from was[128][32]
    __shared__ float t[32][33];
    int iloc = tid >> 3, c4 = (tid & 7) * 4;
    *(float4*)&t[iloc][c4] = *(const float4*)(was + (size_t)(slab * 32 + iloc) * 32 + c4);
    __syncthreads();
    int a = tid & 31, ch = tid >> 5;
    short p[4];
#pragma unroll
    for (int k = 0; k < 4; k++) p[k] = f2b(t[ch * 4 + k][a]);
    *(s16x4*)(Wt + (size_t)7 * 16384 + (size_t)a * 128 + slab * 32 + ch * 4) = *(s16x4*)p;
  } else {
    const float* src = m == 0 ? wo0 : m == 1 ? wq1 : m == 2 ? wk1
                     : m == 3 ? wv1 : m == 4 ? wo1 : m == 5 ? wti : wto + IND * FD;
    __shared__ float t[32][132];
    int r = tid >> 3, c16 = (tid & 7) * 16;
    const float4* s4 = (const float4*)(src + (size_t)(slab * 32 + r) * 128 + c16);
#pragma unroll
    for (int jj = 0; jj < 4; jj++) *(float4*)&t[r][c16 + jj * 4] = s4[jj];
    __syncthreads();
    int f = tid >> 1, ih = (tid & 1) * 16;
    short p[16];
#pragma unroll
    for (int k = 0; k < 16; k++) p[k] = f2b(t[ih + k][f]);
    ushortt* dst = Wt + (size_t)m * 16384 + (size_t)f * 128 + slab * 32 + ih;
    *(bf16x8*)dst = *(bf16x8*)&p[0];
    *(bf16x8*)(dst + 8) = *(bf16x8*)&p[8];
  }
}

// ---- proj16: 8 rows/block; writes Q fp32, K bf16 row-major, V^T bf16 ----
__global__ void proj16_k(const float* __restrict__ X,
                         const float* __restrict__ wq, const float* __restrict__ bq,
                         const float* __restrict__ wk, const float* __restrict__ bk,
                         const float* __restrict__ wv, const float* __restrict__ bv,
                         float* __restrict__ Q, ushortt* __restrict__ Kb,
                         ushortt* __restrict__ Vt) {
  int base = blockIdx.x * 8;
  int b = base >> 9;
  int tloc = base & 511;
  int f = threadIdx.x;
  __shared__ float xs[8][IND];
  {
    int rr = f >> 4, ii = f & 15;
    xs[rr][ii] = X[(size_t)(base + rr) * IND + ii];
  }
  __syncthreads();
  float qa[8], ka[8], va[8];
  float bqf = bq[f], bkf = bk[f], bvf = bv[f];
#pragma unroll
  for (int rr = 0; rr < 8; rr++) { qa[rr] = bqf; ka[rr] = bkf; va[rr] = bvf; }
#pragma unroll
  for (int i = 0; i < IND; i++) {
    float wqv = wq[i * FD + f], wkv = wk[i * FD + f], wvv = wv[i * FD + f];
#pragma unroll
    for (int rr = 0; rr < 8; rr++) {
      float x = xs[rr][i];
      qa[rr] += x * wqv; ka[rr] += x * wkv; va[rr] += x * wvv;
    }
  }
  short vp[8];
#pragma unroll
  for (int rr = 0; rr < 8; rr++) {
    size_t o = (size_t)(base + rr) * FD + f;
    Q[o] = qa[rr];
    Kb[o] = (ushortt)f2b(ka[rr]);
    vp[rr] = f2b(va[rr]);
  }
  *(bf16x8*)&Vt[((size_t)(b * FD) + f) * 512 + tloc] = *(bf16x8*)vp;
}

// ---- MFMA bf16 flash attention v4 (r10) ----
__global__ __launch_bounds__(256, 2) void attn_k(const float* __restrict__ Q,
                                                 const ushortt* __restrict__ Kb,
                                                 const ushortt* __restrict__ Vt,
                                                 const float* __restrict__ mask,
                                                 float* __restrict__ Ores) {
  int b = blockIdx.x >> 4;
  int qt = blockIdx.x & 15;
  int tid = threadIdx.x;
  int w = tid >> 6;
  int lane = tid & 63;
  int l15 = lane & 15, g = lane >> 4;

  __shared__ __align__(16) short q_s[32 * 136];
  __shared__ __align__(16) short k_s[2][32 * 136];
  __shared__ __align__(16) short vt_s[2][128 * 40];
  __shared__ __align__(16) short p_s[4][32 * 40];
  __shared__ __align__(16) float msk_s[512];
  __shared__ __align__(16) float xch[4][32];

  const float scale = 0.17677669529663688f;

  msk_s[tid] = mask[b * TT + tid];
  msk_s[256 + tid] = mask[b * TT + 256 + tid];

  int sr = tid >> 3, sc8 = tid & 7;
  size_t qbase = ((size_t)(b * TT + qt * 32 + sr)) * FD + sc8 * 16;
  {
    const float4* src = (const float4*)(Q + qbase);
#pragma unroll
    for (int jj = 0; jj < 4; jj++) {
      float4 v4 = src[jj];
      *(s16x4*)&q_s[sr * 136 + sc8 * 16 + jj * 4] =
          (s16x4){f2b(v4.x * scale), f2b(v4.y * scale), f2b(v4.z * scale),
                  f2b(v4.w * scale)};
    }
  }

  bf16x8 kr[2], vr[2];
  const ushortt* KbB = Kb + (size_t)b * TT * FD;
  const ushortt* VtB = Vt + (size_t)b * FD * 512;

#define LOAD_TILE(kt)                                                              \
  {                                                                                \
    const ushortt* kbp = KbB + (size_t)(kt) * 32 * FD;                             \
    _Pragma("unroll") for (int is = 0; is < 2; is++) {                             \
      int idx = tid + is * 256;                                                    \
      kr[is] = *(const bf16x8*)(kbp + (idx >> 4) * FD + (idx & 15) * 8);           \
      vr[is] = *(const bf16x8*)(VtB + (size_t)(idx >> 2) * 512 + (kt) * 32 +       \
                                (idx & 3) * 8);                                    \
    }                                                                              \
  }
#define WRITE_TILE(buf)                                                            \
  {                                                                                \
    _Pragma("unroll") for (int is = 0; is < 2; is++) {                             \
      int idx = tid + is * 256;                                                    \
      *(bf16x8*)&k_s[buf][(idx >> 4) * 136 + (idx & 15) * 8] = kr[is];             \
      *(bf16x8*)&vt_s[buf][(idx >> 2) * 40 + (idx & 3) * 8] = vr[is];              \
    }                                                                              \
  }

  LOAD_TILE(0);
  WRITE_TILE(0);

  f32x4 o00 = {0.f, 0.f, 0.f, 0.f}, o01 = o00, o10 = o00, o11 = o00;
  float m0 = -1e30f, m1 = -1e30f, l0 = 0.f, l1 = 0.f;

  bf16x8 aq0, aq1;
  int cur = 0;

  for (int kt = 0; kt < 16; kt++) {
    __syncthreads();
    if (kt == 0) {
      aq0 = *(const bf16x8*)&q_s[l15 * 136 + w * 32 + g * 8];
      aq1 = *(const bf16x8*)&q_s[(16 + l15) * 136 + w * 32 + g * 8];
    }
    if (kt < 15) LOAD_TILE(kt + 1);

    bf16x8 bk0 = *(const bf16x8*)&k_s[cur][l15 * 136 + w * 32 + g * 8];
    bf16x8 bk1 = *(const bf16x8*)&k_s[cur][(16 + l15) * 136 + w * 32 + g * 8];
    f32x4 zero = {0.f, 0.f, 0.f, 0.f};
    f32x4 st00 = MFMA_16x16x32(bk0, aq0, zero);
    f32x4 st01 = MFMA_16x16x32(bk0, aq1, zero);
    f32x4 st10 = MFMA_16x16x32(bk1, aq0, zero);
    f32x4 st11 = MFMA_16x16x32(bk1, aq1, zero);

    float4 mk0 = *(const float4*)&msk_s[kt * 32 + 4 * g];
    float4 mk1 = *(const float4*)&msk_s[kt * 32 + 16 + 4 * g];
    float x0[8], x1[8];
#pragma unroll
    for (int r = 0; r < 4; r++) {
      x0[r] = mk0[r] > 0.f ? st00[r] : -1e9f;
      x0[4 + r] = mk1[r] > 0.f ? st10[r] : -1e9f;
      x1[r] = mk0[r] > 0.f ? st01[r] : -1e9f;
      x1[4 + r] = mk1[r] > 0.f ? st11[r] : -1e9f;
    }
    float lm0 = x0[0], lm1 = x1[0];
#pragma unroll
    for (int i = 1; i < 8; i++) { lm0 = fmaxf(lm0, x0[i]); lm1 = fmaxf(lm1, x1[i]); }
    lm0 = fmaxf(lm0, __shfl_xor(lm0, 16));
    lm0 = fmaxf(lm0, __shfl_xor(lm0, 32));
    lm1 = fmaxf(lm1, __shfl_xor(lm1, 16));
    lm1 = fmaxf(lm1, __shfl_xor(lm1, 32));
    bool need = (lm0 > m0 + 8.f) || (lm1 > m1 + 8.f);
    if (__any(need)) {
      float mn0 = fmaxf(m0, lm0), mn1 = fmaxf(m1, lm1);
      float scv0 = __expf(m0 - mn0), scv1 = __expf(m1 - mn1);
      m0 = mn0; m1 = mn1;
      l0 *= scv0; l1 *= scv1;
      if (lane < 16) { xch[w][l15] = scv0; xch[w][16 + l15] = scv1; }
      float4 sa = *(const float4*)&xch[w][4 * g];
      float4 sb = *(const float4*)&xch[w][16 + 4 * g];
#pragma unroll
      for (int r = 0; r < 4; r++) {
        o00[r] *= sa[r]; o01[r] *= sa[r];
        o10[r] *= sb[r]; o11[r] *= sb[r];
      }
    }
    float p0[8], p1[8];
    float rs0 = 0.f, rs1 = 0.f;
#pragma unroll
    for (int i = 0; i < 8; i++) {
      p0[i] = __expf(x0[i] - m0); rs0 += p0[i];
      p1[i] = __expf(x1[i] - m1); rs1 += p1[i];
    }
    rs0 += __shfl_xor(rs0, 16); rs0 += __shfl_xor(rs0, 32);
    rs1 += __shfl_xor(rs1, 16); rs1 += __shfl_xor(rs1, 32);
    l0 += rs0; l1 += rs1;
    {
      uintt a0 = ((uintt)(ushortt)f2b(p0[1]) << 16) | (ushortt)f2b(p0[0]);
      uintt a1 = ((uintt)(ushortt)f2b(p0[3]) << 16) | (ushortt)f2b(p0[2]);
      uintt a2 = ((uintt)(ushortt)f2b(p0[5]) << 16) | (ushortt)f2b(p0[4]);
      uintt a3 = ((uintt)(ushortt)f2b(p0[7]) << 16) | (ushortt)f2b(p0[6]);
      uintt b0 = ((uintt)(ushortt)f2b(p1[1]) << 16) | (ushortt)f2b(p1[0]);
      uintt b1 = ((uintt)(ushortt)f2b(p1[3]) << 16) | (ushortt)f2b(p1[2]);
      uintt b2 = ((uintt)(ushortt)f2b(p1[5]) << 16) | (ushortt)f2b(p1[4]);
      uintt b3 = ((uintt)(ushortt)f2b(p1[7]) << 16) | (ushortt)f2b(p1[6]);
      *(uint2*)&p_s[w][l15 * 40 + 4 * g] = make_uint2(a0, a1);
      *(uint2*)&p_s[w][l15 * 40 + 16 + 4 * g] = make_uint2(a2, a3);
      *(uint2*)&p_s[w][(16 + l15) * 40 + 4 * g] = make_uint2(b0, b1);
      *(uint2*)&p_s[w][(16 + l15) * 40 + 16 + 4 * g] = make_uint2(b2, b3);
    }
    bf16x8 ap0 = *(const bf16x8*)&p_s[w][l15 * 40 + g * 8];
    bf16x8 ap1 = *(const bf16x8*)&p_s[w][(16 + l15) * 40 + g * 8];
    bf16x8 bv0 = *(const bf16x8*)&vt_s[cur][(w * 32 + l15) * 40 + g * 8];
    bf16x8 bv1 = *(const bf16x8*)&vt_s[cur][(w * 32 + 16 + l15) * 40 + g * 8];
    o00 = MFMA_16x16x32(ap0, bv0, o00);
    o01 = MFMA_16x16x32(ap0, bv1, o01);
    o10 = MFMA_16x16x32(ap1, bv0, o10);
    o11 = MFMA_16x16x32(ap1, bv1, o11);

    if (kt < 15) WRITE_TILE(cur ^ 1);
    cur ^= 1;
  }
  if (lane < 16) { xch[w][l15] = l0; xch[w][16 + l15] = l1; }
  float4 la = *(const float4*)&xch[w][4 * g];
  float4 lb = *(const float4*)&xch[w][16 + 4 * g];
  size_t rowbase = (size_t)(b * TT + qt * 32);
#pragma unroll
  for (int r = 0; r < 4; r++) {
    int q0r = 4 * g + r;
    size_t base0 = (rowbase + q0r) * FD + w * 32 + l15;
    Ores[base0] = Q[base0] + o00[r] / la[r];
    Ores[base0 + 16] = Q[base0 + 16] + o01[r] / la[r];
    int q1r = 16 + 4 * g + r;
    size_t base1 = (rowbase + q1r) * FD + w * 32 + l15;
    Ores[base1] = Q[base1] + o10[r] / lb[r];
    Ores[base1 + 16] = Q[base1 + 16] + o11[r] / lb[r];
  }
#undef LOAD_TILE
#undef WRITE_TILE
}

// LN over 32-row fp32 tile (r10 wave-serial); wave w owns rows w*8..w*8+7.
__device__ __forceinline__ void ln32(float (*A)[132], short (*Xb)[136], int lane, int w,
                                     const float* __restrict__ gg,
                                     const float* __restrict__ bb,
                                     const float* mk, bool applyMask) {
  float ga = gg[lane], gb = gg[lane + 64], ba = bb[lane], b2 = bb[lane + 64];
  for (int j = 0; j < 8; j++) {
    int rr = w * 8 + j;
    float a = A[rr][lane], c = A[rr][lane + 64];
    float s = a + c, ss = a * a + c * c;
#pragma unroll
    for (int o = 32; o > 0; o >>= 1) { s += __shfl_xor(s, o); ss += __shfl_xor(ss, o); }
    float mean = s * (1.f / 128.f);
    float var = ss * (1.f / 128.f) - mean * mean;
    float rs = rsqrtf(var + 1e-5f);
    float m = applyMask ? mk[rr] : 1.f;
    float y0 = ((a - mean) * rs * ga + ba) * m;
    float y1 = ((c - mean) * rs * gb + b2) * m;
    A[rr][lane] = y0; A[rr][lane + 64] = y1;
    Xb[rr][lane] = f2b(y0); Xb[rr][lane + 64] = f2b(y1);
  }
}

// ---- post(layer1) + proj128(layer2), MFMA (r10) ----
__global__ __launch_bounds__(256) void post_proj_k(
    const float* __restrict__ Ores, const float* __restrict__ mask,
    const ushortt* __restrict__ wot, const float* __restrict__ bo,
    const float* __restrict__ g0, const float* __restrict__ be0,
    const float* __restrict__ g1, const float* __restrict__ be1,
    const ushortt* __restrict__ wqt, const float* __restrict__ bq,
    const ushortt* __restrict__ wkt, const float* __restrict__ bk,
    const ushortt* __restrict__ wvt, const float* __restrict__ bv,
    float* __restrict__ Q, ushortt* __restrict__ Kb, ushortt* __restrict__ Vt) {
  int base = blockIdx.x * 32;
  int b = base >> 9;
  int tloc = base & 511;
  int tid = threadIdx.x;
  int w = tid >> 6, lane = tid & 63;
  int l15 = lane & 15, g = lane >> 4;

  __shared__ float A32[32][132];
  __shared__ __align__(16) short Xb[32][136];
  __shared__ float mk[32];

  {
    int r = tid >> 3, c = (tid & 7) * 16;
    const float4* src = (const float4*)(Ores + (size_t)(base + r) * FD + c);
#pragma unroll
    for (int jj = 0; jj < 4; jj++) *(float4*)&A32[r][c + jj * 4] = src[jj];
  }
  if (tid < 32) mk[tid] = mask[base + tid];
  __syncthreads();
  ln32(A32, Xb, lane, w, g0, be0, mk, false);
  __syncthreads();

  int c0 = w * 32 + l15, c1 = c0 + 16;
  f32x4 f00 = {0.f, 0.f, 0.f, 0.f}, f01 = f00, f10 = f00, f11 = f00;
  GEMM128(wot, f00, f01, f10, f11);
  float bo0 = bo[c0], bo1 = bo[c1];
#pragma unroll
  for (int r = 0; r < 4; r++) {
    int r0 = g * 4 + r, r1 = 16 + r0;
    A32[r0][c0] += fmaxf(f00[r] + bo0, 0.f);
    A32[r0][c1] += fmaxf(f01[r] + bo1, 0.f);
    A32[r1][c0] += fmaxf(f10[r] + bo0, 0.f);
    A32[r1][c1] += fmaxf(f11[r] + bo1, 0.f);
  }
  __syncthreads();
  ln32(A32, Xb, lane, w, g1, be1, mk, true);
  __syncthreads();

  {
    f32x4 q00 = {0.f, 0.f, 0.f, 0.f}, q01 = q00, q10 = q00, q11 = q00;
    GEMM128(wqt, q00, q01, q10, q11);
    float bq0 = bq[c0], bq1 = bq[c1];
#pragma unroll
    for (int r = 0; r < 4; r++) {
      int r0 = g * 4 + r, r1 = 16 + r0;
      Q[(size_t)(base + r0) * FD + c0] = q00[r] + bq0;
      Q[(size_t)(base + r0) * FD + c1] = q01[r] + bq1;
      Q[(size_t)(base + r1) * FD + c0] = q10[r] + bq0;
      Q[(size_t)(base + r1) * FD + c1] = q11[r] + bq1;
    }
  }
  {
    f32x4 k00 = {0.f, 0.f, 0.f, 0.f}, k01 = k00, k10 = k00, k11 = k00;
    GEMM128(wkt, k00, k01, k10, k11);
    float bk0 = bk[c0], bk1 = bk[c1];
#pragma unroll
    for (int r = 0; r < 4; r++) {
      int r0 = g * 4 + r, r1 = 16 + r0;
      Kb[(size_t)(base + r0) * FD + c0] = (ushortt)f2b(k00[r] + bk0);
      Kb[(size_t)(base + r0) * FD + c1] = (ushortt)f2b(k01[r] + bk1);
      Kb[(size_t)(base + r1) * FD + c0] = (ushortt)f2b(k10[r] + bk0);
      Kb[(size_t)(base + r1) * FD + c1] = (ushortt)f2b(k11[r] + bk1);
    }
  }
  {
    f32x4 v00 = {0.f, 0.f, 0.f, 0.f}, v01 = v00, v10 = v00, v11 = v00;
    GEMM128(wvt, v00, v01, v10, v11);
    float bv0 = bv[c0], bv1 = bv[c1];
    short p[4];
#pragma unroll
    for (int k = 0; k < 4; k++) p[k] = f2b(v00[k] + bv0);
    *(s16x4*)&Vt[((size_t)b * FD + c0) * 512 + tloc + g * 4] = *(s16x4*)p;
#pragma unroll
    for (int k = 0; k < 4; k++) p[k] = f2b(v01[k] + bv1);
    *(s16x4*)&Vt[((size_t)b * FD + c1) * 512 + tloc + g * 4] = *(s16x4*)p;
#pragma unroll
    for (int k = 0; k < 4; k++) p[k] = f2b(v10[k] + bv0);
    *(s16x4*)&Vt[((size_t)b * FD + c0) * 512 + tloc + 16 + g * 4] = *(s16x4*)p;
#pragma unroll
    for (int k = 0; k < 4; k++) p[k] = f2b(v11[k] + bv1);
    *(s16x4*)&Vt[((size_t)b * FD + c1) * 512 + tloc + 16 + g * 4] = *(s16x4*)p;
  }
}

// ---- post(layer2) + ti + as-score, MFMA (r10 + race fix) ----
__global__ __launch_bounds__(256) void post_ti_k(
    const float* __restrict__ Ores, const float* __restrict__ mask,
    const ushortt* __restrict__ wot, const float* __restrict__ bo,
    const float* __restrict__ g0, const float* __restrict__ be0,
    const float* __restrict__ g1, const float* __restrict__ be1,
    const ushortt* __restrict__ wtit, const float* __restrict__ bti,
    const ushortt* __restrict__ wast, const float* __restrict__ bas,
    float* __restrict__ Xp2, float* __restrict__ S) {
  int base = blockIdx.x * 32;
  int tid = threadIdx.x;
  int w = tid >> 6, lane = tid & 63;
  int l15 = lane & 15, g = lane >> 4;

  __shared__ float A32[32][132];
  __shared__ __align__(16) short Xb[32][136];
  __shared__ float mk[32];

  {
    int r = tid >> 3, c = (tid & 7) * 16;
    const float4* src = (const float4*)(Ores + (size_t)(base + r) * FD + c);
#pragma unroll
    for (int jj = 0; jj < 4; jj++) *(float4*)&A32[r][c + jj * 4] = src[jj];
  }
  if (tid < 32) mk[tid] = mask[base + tid];
  __syncthreads();
  ln32(A32, Xb, lane, w, g0, be0, mk, false);
  __syncthreads();

  int c0 = w * 32 + l15, c1 = c0 + 16;
  f32x4 f00 = {0.f, 0.f, 0.f, 0.f}, f01 = f00, f10 = f00, f11 = f00;
  GEMM128(wot, f00, f01, f10, f11);
  float bo0 = bo[c0], bo1 = bo[c1];
#pragma unroll
  for (int r = 0; r < 4; r++) {
    int r0 = g * 4 + r, r1 = 16 + r0;
    A32[r0][c0] += fmaxf(f00[r] + bo0, 0.f);
    A32[r0][c1] += fmaxf(f01[r] + bo1, 0.f);
    A32[r1][c0] += fmaxf(f10[r] + bo0, 0.f);
    A32[r1][c1] += fmaxf(f11[r] + bo1, 0.f);
  }
  __syncthreads();
  ln32(A32, Xb, lane, w, g1, be1, mk, true);
  __syncthreads();

  // ti GEMM reads Xb (Xp); hold outputs in regs, write Xb only after barrier
  f32x4 t00 = {0.f, 0.f, 0.f, 0.f}, t01 = t00, t10 = t00, t11 = t00;
  GEMM128(wtit, t00, t01, t10, t11);
  float bti0 = bti[c0], bti1 = bti[c1];
  short pk[16];
#pragma unroll
  for (int r = 0; r < 4; r++) {
    int r0 = g * 4 + r, r1 = 16 + r0;
    float v00 = (t00[r] + bti0) * mk[r0];
    float v01 = (t01[r] + bti1) * mk[r0];
    float v10 = (t10[r] + bti0) * mk[r1];
    float v11 = (t11[r] + bti1) * mk[r1];
    Xp2[(size_t)(base + r0) * FD + c0] = v00;
    Xp2[(size_t)(base + r0) * FD + c1] = v01;
    Xp2[(size_t)(base + r1) * FD + c0] = v10;
    Xp2[(size_t)(base + r1) * FD + c1] = v11;
    pk[r * 4 + 0] = f2b(v00);
    pk[r * 4 + 1] = f2b(v01);
    pk[r * 4 + 2] = f2b(v10);
    pk[r * 4 + 3] = f2b(v11);
  }
  __syncthreads();  // RACE FIX: all waves' ti-GEMM Xb reads complete before overwrite
#pragma unroll
  for (int r = 0; r < 4; r++) {
    int r0 = g * 4 + r, r1 = 16 + r0;
    Xb[r0][c0] = pk[r * 4 + 0];
    Xb[r0][c1] = pk[r * 4 + 1];
    Xb[r1][c0] = pk[r * 4 + 2];
    Xb[r1][c1] = pk[r * 4 + 3];
  }
  __syncthreads();
  if (w < 2) {
    int a0 = w * 16 + l15;
    f32x4 s0 = {0.f, 0.f, 0.f, 0.f}, s1 = s0;
#pragma unroll
    for (int ks = 0; ks < 4; ks++) {
      bf16x8 aa0 = *(const bf16x8*)&Xb[l15][ks * 32 + g * 8];
      bf16x8 aa1 = *(const bf16x8*)&Xb[16 + l15][ks * 32 + g * 8];
      bf16x8 bb0 = *(const bf16x8*)(wast + (size_t)a0 * 128 + ks * 32 + g * 8);
      s0 = MFMA_16x16x32(aa0, bb0, s0);
      s1 = MFMA_16x16x32(aa1, bb0, s1);
    }
    float bas0 = bas[a0];
#pragma unroll
    for (int r = 0; r < 4; r++) {
      int r0 = g * 4 + r;
      S[(size_t)(base + r0) * NAGG + a0] = s0[r] + bas0;
      S[(size_t)(base + 16 + r0) * NAGG + a0] = s1[r] + bas0;
    }
  }
}

// ---- soft_t ----
__global__ void soft_t(const float* __restrict__ S, const float* __restrict__ mask,
                       float* __restrict__ att) {
  int b = blockIdx.x >> 5, a = blockIdx.x & 31;
  int tid = threadIdx.x;  // 128
  __shared__ float red[2];
  float sv[4], mv[4];
#pragma unroll
  for (int j = 0; j < 4; j++) {
    int t = tid + j * 128;
    sv[j] = S[(size_t)(b * TT + t) * NAGG + a];
    mv[j] = mask[b * TT + t];
  }
  float mx = fmaxf(fmaxf(sv[0], sv[1]), fmaxf(sv[2], sv[3]));
#pragma unroll
  for (int o = 32; o > 0; o >>= 1) mx = fmaxf(mx, __shfl_xor(mx, o));
  if ((tid & 63) == 0) red[tid >> 6] = mx;
  __syncthreads();
  mx = fmaxf(red[0], red[1]);
  __syncthreads();
  float e[4];
  float sm = 0.f;
#pragma unroll
  for (int j = 0; j < 4; j++) {
    e[j] = __expf(sv[j] - mx) * mv[j];
    sm += e[j];
  }
#pragma unroll
  for (int o = 32; o > 0; o >>= 1) sm += __shfl_xor(sm, o);
  if ((tid & 63) == 0) red[tid >> 6] = sm;
  __syncthreads();
  float inv = 1.f / (red[0] + red[1] + 1e-16f);
  float* dst = att + ((size_t)(b * NAGG + a)) * TT;
#pragma unroll
  for (int j = 0; j < 4; j++) dst[tid + j * 128] = e[j] * inv;
}

// ---- pool_part (r10) ----
__global__ void pool_part_k(const float* __restrict__ Xp2, const float* __restrict__ att,
                            const float* __restrict__ mask,
                            float* __restrict__ pmax, float* __restrict__ pmin,
                            float* __restrict__ psum) {
  int bid = blockIdx.x;
  int b = bid >> 7;
  int a = (bid >> 2) & 31;
  int tc = bid & 3;
  int f = threadIdx.x;
  __shared__ float att_s[128];
  __shared__ float ms[128];
  att_s[f] = att[((size_t)(b * NAGG + a)) * TT + tc * 128 + f];
  ms[f] = mask[b * TT + tc * 128 + f];
  __syncthreads();
  const float* xp = Xp2 + ((size_t)(b * TT + tc * 128)) * FD + f;
  float mn = 1e30f, mx = -1e30f, sm = 0.f;
#pragma unroll 4
  for (int t = 0; t < 128; t++) {
    float e = xp[(size_t)t * FD] * att_s[t];
    mn = fminf(mn, e);
    bool keep = ms[t] > 0.f;
    mx = keep ? fmaxf(mx, e) : mx;
    sm = keep ? sm + e : sm;
  }
  size_t idx = (size_t)bid * 128 + f;
  pmax[idx] = mx;
  pmin[idx] = mn;
  psum[idx] = sm;
}

// ---- combine (r10) ----
__global__ void combine_k(const float* __restrict__ pmax, const float* __restrict__ pmin,
                          const float* __restrict__ psum, const float* __restrict__ mask,
                          float* __restrict__ aggF, float* __restrict__ agg_out) {
  int b = blockIdx.x >> 5, a = blockIdx.x & 31;
  int f = threadIdx.x;
  __shared__ float red[2];
  float ntp = 0.f;
#pragma unroll
  for (int j = 0; j < 4; j++) ntp += (mask[b * TT + f + j * 128] > 0.f) ? 1.f : 0.f;
#pragma unroll
  for (int o = 32; o > 0; o >>= 1) ntp += __shfl_xor(ntp, o);
  if ((f & 63) == 0) red[f >> 6] = ntp;
  __syncthreads();
  float nt = red[0] + red[1];
  float mx = -1e30f, mn = 1e30f, sm = 0.f;
#pragma unroll
  for (int tc = 0; tc < 4; tc++) {
    size_t idx = ((size_t)(b * 128 + a * 4 + tc)) * 128 + f;
    mx = fmaxf(mx, pmax[idx]);
    mn = fminf(mn, pmin[idx]);
    sm += psum[idx];
  }
  bool anyUn = nt < 511.5f;
  float mp = anyUn ? fmaxf(mx, mn - 1.f) : mx;
  float mean = sm / (nt == 0.f ? 1.f : nt);
  size_t bs = (size_t)b * 8192 + (size_t)a * 256;
  aggF[bs + f] = mp;
  aggF[bs + 128 + f] = mean;
  agg_out[bs + f] = mp;
  agg_out[bs + 128 + f] = mean;
}

// ---- aggmm ----
__global__ void aggmm_k(const float* __restrict__ aggF, const float* __restrict__ wto,
                        float* __restrict__ part) {
  int b = blockIdx.x >> 5, cc = blockIdx.x & 31;
  int f = threadIdx.x;
  __shared__ float ag[256];
  ag[f] = aggF[(size_t)b * 8192 + cc * 256 + f];
  ag[128 + f] = aggF[(size_t)b * 8192 + cc * 256 + 128 + f];
  __syncthreads();
  const float* w = wto + ((size_t)(IND + FD) + cc * 256) * FD;
  float a0 = 0.f, a1 = 0.f, a2 = 0.f, a3 = 0.f;
#pragma unroll 4
  for (int j = 0; j < 256; j += 4) {
    a0 += ag[j] * w[(size_t)j * FD + f];
    a1 += ag[j + 1] * w[(size_t)(j + 1) * FD + f];
    a2 += ag[j + 2] * w[(size_t)(j + 2) * FD + f];
    a3 += ag[j + 3] * w[(size_t)(j + 3) * FD + f];
  }
  part[(size_t)(b * 32 + cc) * FD + f] = (a0 + a1) + (a2 + a3);
}

// ---- final, MFMA (r10 wave-serial LN tail) ----
__global__ __launch_bounds__(256) void final_k(
    const float* __restrict__ X, const float* __restrict__ Xp2,
    const float* __restrict__ part, const ushortt* __restrict__ wtot,
    const float* __restrict__ wto, const float* __restrict__ bto,
    const float* __restrict__ gto, const float* __restrict__ btoln,
    const float* __restrict__ mask, float* __restrict__ out) {
  int base = blockIdx.x * 32;
  int b = base >> 9;
  int tid = threadIdx.x;
  int w = tid >> 6, lane = tid & 63;
  int l15 = lane & 15, g = lane >> 4;
  __shared__ float A32[32][132];
  __shared__ __align__(16) short Xb[32][136];
  __shared__ float xss[32][17];
  __shared__ float psum_s[128];
  __shared__ float mk[32];
  {
    int r = tid >> 3, c = (tid & 7) * 16;
    const float4* src = (const float4*)(Xp2 + (size_t)(base + r) * FD + c);
#pragma unroll
    for (int jj = 0; jj < 4; jj++) {
      float4 v = src[jj];
      *(s16x4*)&Xb[r][c + jj * 4] = (s16x4){f2b(v.x), f2b(v.y), f2b(v.z), f2b(v.w)};
    }
  }
  {
    int r = tid >> 3, ii = (tid & 7) * 2;
    xss[r][ii] = X[(size_t)(base + r) * IND + ii];
    xss[r][ii + 1] = X[(size_t)(base + r) * IND + ii + 1];
  }
  if (tid < 32) mk[tid] = mask[base + tid];
  if (tid < 128) {
    float ps = 0.f;
#pragma unroll 8
    for (int cc = 0; cc < 32; cc++) ps += part[(size_t)(b * 32 + cc) * FD + tid];
    psum_s[tid] = ps;
  }
  __syncthreads();
  int c0 = w * 32 + l15, c1 = c0 + 16;
  f32x4 q00 = {0.f, 0.f, 0.f, 0.f}, q01 = q00, q10 = q00, q11 = q00;
  GEMM128(wtot, q00, q01, q10, q11);
  float wx0[16], wx1[16];
#pragma unroll
  for (int i = 0; i < 16; i++) { wx0[i] = wto[i * FD + c0]; wx1[i] = wto[i * FD + c1]; }
  float add0 = bto[c0] + psum_s[c0], add1 = bto[c1] + psum_s[c1];
#pragma unroll
  for (int r = 0; r < 4; r++) {
    int r0 = g * 4 + r, r1 = 16 + r0;
    float x00 = q00[r] + add0, x01 = q01[r] + add1;
    float x10 = q10[r] + add0, x11 = q11[r] + add1;
#pragma unroll
    for (int i = 0; i < 16; i++) {
      x00 += xss[r0][i] * wx0[i];
      x01 += xss[r0][i] * wx1[i];
      x10 += xss[r1][i] * wx0[i];
      x11 += xss[r1][i] * wx1[i];
    }
    A32[r0][c0] = x00; A32[r0][c1] = x01;
    A32[r1][c0] = x10; A32[r1][c1] = x11;
  }
  __syncthreads();
  float ga = gto[lane], gb = gto[lane + 64], ba = btoln[lane], bb2 = btoln[lane + 64];
  for (int j = 0; j < 8; j++) {
    int rr = w * 8 + j;
    float a = A32[rr][lane], c = A32[rr][lane + 64];
    float s = a + c, ss = a * a + c * c;
#pragma unroll
    for (int o = 32; o > 0; o >>= 1) { s += __shfl_xor(s, o); ss += __shfl_xor(ss, o); }
    float mean = s * (1.f / 128.f);
    float var = ss * (1.f / 128.f) - mean * mean;
    float rs = rsqrtf(var + 1e-5f);
    float m = mk[rr];
    out[(size_t)(base + rr) * FD + lane] = fmaxf((a - mean) * rs * ga + ba, 0.f) * m;
    out[(size_t)(base + rr) * FD + lane + 64] = fmaxf((c - mean) * rs * gb + bb2, 0.f) * m;
  }
}

extern "C" void kernel_launch(void* const* d_in, const int* in_sizes, int n_in,
                              void* d_out, int out_size, void* d_ws, size_t ws_size,
                              hipStream_t stream) {
  const float* X    = (const float*)d_in[0];
  const float* mask = (const float*)d_in[1];
  const float* wq0 = (const float*)d_in[2];  const float* bq0 = (const float*)d_in[3];
  const float* wk0 = (const float*)d_in[4];  const float* bk0 = (const float*)d_in[5];
  const float* wv0 = (const float*)d_in[6];  const float* bv0 = (const float*)d_in[7];
  const float* wo0 = (const float*)d_in[8];  const float* bo0 = (const float*)d_in[9];
  const float* g00 = (const float*)d_in[10]; const float* be00 = (const float*)d_in[11];
  const float* g10 = (const float*)d_in[12]; const float* be10 = (const float*)d_in[13];
  const float* wq1 = (const float*)d_in[14]; const float* bq1 = (const float*)d_in[15];
  const float* wk1 = (const float*)d_in[16]; const float* bk1 = (const float*)d_in[17];
  const float* wv1 = (const float*)d_in[18]; const float* bv1 = (const float*)d_in[19];
  const float* wo1 = (const float*)d_in[20]; const float* bo1 = (const float*)d_in[21];
  const float* g01 = (const float*)d_in[22]; const float* be01 = (const float*)d_in[23];
  const float* g11 = (const float*)d_in[24]; const float* be11 = (const float*)d_in[25];
  const float* wti = (const float*)d_in[26]; const float* bti = (const float*)d_in[27];
  const float* was = (const float*)d_in[28]; const float* bas = (const float*)d_in[29];
  const float* wto = (const float*)d_in[30]; const float* bto = (const float*)d_in[31];
  const float* gto = (const float*)d_in[32]; const float* btoln = (const float*)d_in[33];

  const size_t BIG = (size_t)BB * TT * FD;  // 2,097,152 floats
  float* ws = (float*)d_ws;
  float* Qf = ws;
  ushortt* Kb = (ushortt*)(ws + BIG);
  ushortt* Vt = (ushortt*)(ws + BIG + BIG / 2);
  float* Ores = Qf;
  float* Xp2 = ws + BIG;
  float* S    = ws + 2 * BIG;
  float* att  = ws + 2 * BIG + 524288;
  float* aggF = ws + 2 * BIG + 1048576;
  float* part = ws + 2 * BIG + 1310720;
  ushortt* Wt = (ushortt*)(ws + 2 * BIG + 1441792);  // 8 x 16384 bf16
  float* pmax = ws;                                  // dead Qf/Ores region
  float* pmin = ws + 524288;
  float* psum = ws + 1048576;

  ushortt* wo0t = Wt;
  ushortt* wq1t = Wt + 16384;
  ushortt* wk1t = Wt + 2 * 16384;
  ushortt* wv1t = Wt + 3 * 16384;
  ushortt* wo1t = Wt + 4 * 16384;
  ushortt* wtit = Wt + 5 * 16384;
  ushortt* wtot = Wt + 6 * 16384;
  ushortt* wast = Wt + 7 * 16384;

  float* out_main = (float*)d_out;
  float* out_agg  = (float*)d_out + BIG;

  int nrb = BB * TT / 8;    // 2048
  int nrb32 = BB * TT / 32; // 512
  prep_w_k<<<32, 256, 0, stream>>>(wo0, wq1, wk1, wv1, wo1, wti, wto, was, Wt);
  proj16_k<<<nrb, 128, 0, stream>>>(X, wq0, bq0, wk0, bk0, wv0, bv0, Qf, Kb, Vt);
  attn_k<<<BB * 16, 256, 0, stream>>>(Qf, Kb, Vt, mask, Ores);
  post_proj_k<<<nrb32, 256, 0, stream>>>(Ores, mask, wo0t, bo0, g00, be00, g10, be10,
                                         wq1t, bq1, wk1t, bk1, wv1t, bv1, Qf, Kb, Vt);
  attn_k<<<BB * 16, 256, 0, stream>>>(Qf, Kb, Vt, mask, Ores);
  post_ti_k<<<nrb32, 256, 0, stream>>>(Ores, mask, wo1t, bo1, g01, be01, g11, be11,
                                       wtit, bti, wast, bas, Xp2, S);
  soft_t<<<BB * NAGG, 128, 0, stream>>>(S, mask, att);
  pool_part_k<<<BB * NAGG * 4, 128, 0, stream>>>(Xp2, att, mask, pmax, pmin, psum);
  combine_k<<<BB * NAGG, 128, 0, stream>>>(pmax, pmin, psum, mask, aggF, out_agg);
  aggmm_k<<<BB * 32, 128, 0, stream>>>(aggF, wto, part);
  final_k<<<nrb32, 256, 0, stream>>>(X, Xp2, part, wtot, wto, bto, gto, btoln, mask, out_main);
}

// Round 16
// 144.818 us; speedup vs baseline: 1.0014x; 1.0014x over previous
//
#include <hip/hip_runtime.h>
#include <hip/hip_bf16.h>

#define BB 32
#define TT 512
#define IND 16
#define FD 128
#define NAGG 32

typedef unsigned short ushortt;
typedef unsigned int uintt;
typedef __attribute__((ext_vector_type(8))) short bf16x8;
typedef __attribute__((ext_vector_type(4))) short s16x4;
typedef __attribute__((ext_vector_type(4))) float f32x4;

__device__ __forceinline__ short f2b(float x) {
  union { __hip_bfloat16 h; short s; } u;
  u.h = __float2bfloat16(x);
  return u.s;
}

#define MFMA_16x16x32(A, B, C) __builtin_amdgcn_mfma_f32_16x16x32_bf16(A, B, C, 0, 0, 0)

// K=128 GEMM over 32-row LDS tile Xb, cols c0/c1 per wave, frags per m89 mapping.
#define GEMM128(WT, c00, c01, c10, c11)                                        \
  {                                                                            \
    _Pragma("unroll") for (int ks = 0; ks < 4; ks++) {                         \
      bf16x8 a0 = *(const bf16x8*)&Xb[l15][ks * 32 + g * 8];                   \
      bf16x8 a1 = *(const bf16x8*)&Xb[16 + l15][ks * 32 + g * 8];              \
      bf16x8 b0 = *(const bf16x8*)((WT) + (size_t)c0 * 128 + ks * 32 + g * 8); \
      bf16x8 b1 = *(const bf16x8*)((WT) + (size_t)c1 * 128 + ks * 32 + g * 8); \
      c00 = MFMA_16x16x32(a0, b0, c00);                                        \
      c01 = MFMA_16x16x32(a0, b1, c01);                                        \
      c10 = MFMA_16x16x32(a1, b0, c10);                                        \
      c11 = MFMA_16x16x32(a1, b1, c11);                                        \
    }                                                                          \
  }

// ---- prep: transpose weights to bf16 W^T. grid 8*4, 256 thr ----
__global__ void prep_w_k(const float* __restrict__ wo0, const float* __restrict__ wq1,
                         const float* __restrict__ wk1, const float* __restrict__ wv1,
                         const float* __restrict__ wo1, const float* __restrict__ wti,
                         const float* __restrict__ wto, const float* __restrict__ was,
                         ushortt* __restrict__ Wt) {
  int m = blockIdx.x >> 2;
  int slab = blockIdx.x & 3;
  int tid = threadIdx.x;
  if (m == 7) {  // wast[32][128] from was[128][32]
    __shared__ float t[32][33];
    int iloc = tid >> 3, c4 = (tid & 7) * 4;
    *(float4*)&t[iloc][c4] = *(const float4*)(was + (size_t)(slab * 32 + iloc) * 32 + c4);
    __syncthreads();
    int a = tid & 31, ch = tid >> 5;
    short p[4];
#pragma unroll
    for (int k = 0; k < 4; k++) p[k] = f2b(t[ch * 4 + k][a]);
    *(s16x4*)(Wt + (size_t)7 * 16384 + (size_t)a * 128 + slab * 32 + ch * 4) = *(s16x4*)p;
  } else {
    const float* src = m == 0 ? wo0 : m == 1 ? wq1 : m == 2 ? wk1
                     : m == 3 ? wv1 : m == 4 ? wo1 : m == 5 ? wti : wto + IND * FD;
    __shared__ float t[32][132];
    int r = tid >> 3, c16 = (tid & 7) * 16;
    const float4* s4 = (const float4*)(src + (size_t)(slab * 32 + r) * 128 + c16);
#pragma unroll
    for (int jj = 0; jj < 4; jj++) *(float4*)&t[r][c16 + jj * 4] = s4[jj];
    __syncthreads();
    int f = tid >> 1, ih = (tid & 1) * 16;
    short p[16];
#pragma unroll
    for (int k = 0; k < 16; k++) p[k] = f2b(t[ih + k][f]);
    ushortt* dst = Wt + (size_t)m * 16384 + (size_t)f * 128 + slab * 32 + ih;
    *(bf16x8*)dst = *(bf16x8*)&p[0];
    *(bf16x8*)(dst + 8) = *(bf16x8*)&p[8];
  }
}

// ---- proj16: 8 rows/block; writes Q fp32, K bf16 row-major, V^T bf16 ----
__global__ void proj16_k(const float* __restrict__ X,
                         const float* __restrict__ wq, const float* __restrict__ bq,
                         const float* __restrict__ wk, const float* __restrict__ bk,
                         const float* __restrict__ wv, const float* __restrict__ bv,
                         float* __restrict__ Q, ushortt* __restrict__ Kb,
                         ushortt* __restrict__ Vt) {
  int base = blockIdx.x * 8;
  int b = base >> 9;
  int tloc = base & 511;
  int f = threadIdx.x;
  __shared__ float xs[8][IND];
  {
    int rr = f >> 4, ii = f & 15;
    xs[rr][ii] = X[(size_t)(base + rr) * IND + ii];
  }
  __syncthreads();
  float qa[8], ka[8], va[8];
  float bqf = bq[f], bkf = bk[f], bvf = bv[f];
#pragma unroll
  for (int rr = 0; rr < 8; rr++) { qa[rr] = bqf; ka[rr] = bkf; va[rr] = bvf; }
#pragma unroll
  for (int i = 0; i < IND; i++) {
    float wqv = wq[i * FD + f], wkv = wk[i * FD + f], wvv = wv[i * FD + f];
#pragma unroll
    for (int rr = 0; rr < 8; rr++) {
      float x = xs[rr][i];
      qa[rr] += x * wqv; ka[rr] += x * wkv; va[rr] += x * wvv;
    }
  }
  short vp[8];
#pragma unroll
  for (int rr = 0; rr < 8; rr++) {
    size_t o = (size_t)(base + rr) * FD + f;
    Q[o] = qa[rr];
    Kb[o] = (ushortt)f2b(ka[rr]);
    vp[rr] = f2b(va[rr]);
  }
  *(bf16x8*)&Vt[((size_t)(b * FD) + f) * 512 + tloc] = *(bf16x8*)vp;
}

// ---- MFMA bf16 flash attention v4 (r10) ----
__global__ __launch_bounds__(256, 2) void attn_k(const float* __restrict__ Q,
                                                 const ushortt* __restrict__ Kb,
                                                 const ushortt* __restrict__ Vt,
                                                 const float* __restrict__ mask,
                                                 float* __restrict__ Ores) {
  int b = blockIdx.x >> 4;
  int qt = blockIdx.x & 15;
  int tid = threadIdx.x;
  int w = tid >> 6;
  int lane = tid & 63;
  int l15 = lane & 15, g = lane >> 4;

  __shared__ __align__(16) short q_s[32 * 136];
  __shared__ __align__(16) short k_s[2][32 * 136];
  __shared__ __align__(16) short vt_s[2][128 * 40];
  __shared__ __align__(16) short p_s[4][32 * 40];
  __shared__ __align__(16) float msk_s[512];
  __shared__ __align__(16) float xch[4][32];

  const float scale = 0.17677669529663688f;

  msk_s[tid] = mask[b * TT + tid];
  msk_s[256 + tid] = mask[b * TT + 256 + tid];

  int sr = tid >> 3, sc8 = tid & 7;
  size_t qbase = ((size_t)(b * TT + qt * 32 + sr)) * FD + sc8 * 16;
  {
    const float4* src = (const float4*)(Q + qbase);
#pragma unroll
    for (int jj = 0; jj < 4; jj++) {
      float4 v4 = src[jj];
      *(s16x4*)&q_s[sr * 136 + sc8 * 16 + jj * 4] =
          (s16x4){f2b(v4.x * scale), f2b(v4.y * scale), f2b(v4.z * scale),
                  f2b(v4.w * scale)};
    }
  }

  bf16x8 kr[2], vr[2];
  const ushortt* KbB = Kb + (size_t)b * TT * FD;
  const ushortt* VtB = Vt + (size_t)b * FD * 512;

#define LOAD_TILE(kt)                                                              \
  {                                                                                \
    const ushortt* kbp = KbB + (size_t)(kt) * 32 * FD;                             \
    _Pragma("unroll") for (int is = 0; is < 2; is++) {                             \
      int idx = tid + is * 256;                                                    \
      kr[is] = *(const bf16x8*)(kbp + (idx >> 4) * FD + (idx & 15) * 8);           \
      vr[is] = *(const bf16x8*)(VtB + (size_t)(idx >> 2) * 512 + (kt) * 32 +       \
                                (idx & 3) * 8);                                    \
    }                                                                              \
  }
#define WRITE_TILE(buf)                                                            \
  {                                                                                \
    _Pragma("unroll") for (int is = 0; is < 2; is++) {                             \
      int idx = tid + is * 256;                                                    \
      *(bf16x8*)&k_s[buf][(idx >> 4) * 136 + (idx & 15) * 8] = kr[is];             \
      *(bf16x8*)&vt_s[buf][(idx >> 2) * 40 + (idx & 3) * 8] = vr[is];              \
    }                                                                              \
  }

  LOAD_TILE(0);
  WRITE_TILE(0);

  f32x4 o00 = {0.f, 0.f, 0.f, 0.f}, o01 = o00, o10 = o00, o11 = o00;
  float m0 = -1e30f, m1 = -1e30f, l0 = 0.f, l1 = 0.f;

  bf16x8 aq0, aq1;
  int cur = 0;

  for (int kt = 0; kt < 16; kt++) {
    __syncthreads();
    if (kt == 0) {
      aq0 = *(const bf16x8*)&q_s[l15 * 136 + w * 32 + g * 8];
      aq1 = *(const bf16x8*)&q_s[(16 + l15) * 136 + w * 32 + g * 8];
    }
    if (kt < 15) LOAD_TILE(kt + 1);

    bf16x8 bk0 = *(const bf16x8*)&k_s[cur][l15 * 136 + w * 32 + g * 8];
    bf16x8 bk1 = *(const bf16x8*)&k_s[cur][(16 + l15) * 136 + w * 32 + g * 8];
    f32x4 zero = {0.f, 0.f, 0.f, 0.f};
    f32x4 st00 = MFMA_16x16x32(bk0, aq0, zero);
    f32x4 st01 = MFMA_16x16x32(bk0, aq1, zero);
    f32x4 st10 = MFMA_16x16x32(bk1, aq0, zero);
    f32x4 st11 = MFMA_16x16x32(bk1, aq1, zero);

    float4 mk0 = *(const float4*)&msk_s[kt * 32 + 4 * g];
    float4 mk1 = *(const float4*)&msk_s[kt * 32 + 16 + 4 * g];
    float x0[8], x1[8];
#pragma unroll
    for (int r = 0; r < 4; r++) {
      x0[r] = mk0[r] > 0.f ? st00[r] : -1e9f;
      x0[4 + r] = mk1[r] > 0.f ? st10[r] : -1e9f;
      x1[r] = mk0[r] > 0.f ? st01[r] : -1e9f;
      x1[4 + r] = mk1[r] > 0.f ? st11[r] : -1e9f;
    }
    float lm0 = x0[0], lm1 = x1[0];
#pragma unroll
    for (int i = 1; i < 8; i++) { lm0 = fmaxf(lm0, x0[i]); lm1 = fmaxf(lm1, x1[i]); }
    lm0 = fmaxf(lm0, __shfl_xor(lm0, 16));
    lm0 = fmaxf(lm0, __shfl_xor(lm0, 32));
    lm1 = fmaxf(lm1, __shfl_xor(lm1, 16));
    lm1 = fmaxf(lm1, __shfl_xor(lm1, 32));
    bool need = (lm0 > m0 + 8.f) || (lm1 > m1 + 8.f);
    if (__any(need)) {
      float mn0 = fmaxf(m0, lm0), mn1 = fmaxf(m1, lm1);
      float scv0 = __expf(m0 - mn0), scv1 = __expf(m1 - mn1);
      m0 = mn0; m1 = mn1;
      l0 *= scv0; l1 *= scv1;
      if (lane < 16) { xch[w][l15] = scv0; xch[w][16 + l15] = scv1; }
      float4 sa = *(const float4*)&xch[w][4 * g];
      float4 sb = *(const float4*)&xch[w][16 + 4 * g];
#pragma unroll
      for (int r = 0; r < 4; r++) {
        o00[r] *= sa[r]; o01[r] *= sa[r];
        o10[r] *= sb[r]; o11[r] *= sb[r];
      }
    }
    float p0[8], p1[8];
    float rs0 = 0.f, rs1 = 0.f;
#pragma unroll
    for (int i = 0; i < 8; i++) {
      p0[i] = __expf(x0[i] - m0); rs0 += p0[i];
      p1[i] = __expf(x1[i] - m1); rs1 += p1[i];
    }
    rs0 += __shfl_xor(rs0, 16); rs0 += __shfl_xor(rs0, 32);
    rs1 += __shfl_xor(rs1, 16); rs1 += __shfl_xor(rs1, 32);
    l0 += rs0; l1 += rs1;
    {
      uintt a0 = ((uintt)(ushortt)f2b(p0[1]) << 16) | (ushortt)f2b(p0[0]);
      uintt a1 = ((uintt)(ushortt)f2b(p0[3]) << 16) | (ushortt)f2b(p0[2]);
      uintt a2 = ((uintt)(ushortt)f2b(p0[5]) << 16) | (ushortt)f2b(p0[4]);
      uintt a3 = ((uintt)(ushortt)f2b(p0[7]) << 16) | (ushortt)f2b(p0[6]);
      uintt b0 = ((uintt)(ushortt)f2b(p1[1]) << 16) | (ushortt)f2b(p1[0]);
      uintt b1 = ((uintt)(ushortt)f2b(p1[3]) << 16) | (ushortt)f2b(p1[2]);
      uintt b2 = ((uintt)(ushortt)f2b(p1[5]) << 16) | (ushortt)f2b(p1[4]);
      uintt b3 = ((uintt)(ushortt)f2b(p1[7]) << 16) | (ushortt)f2b(p1[6]);
      *(uint2*)&p_s[w][l15 * 40 + 4 * g] = make_uint2(a0, a1);
      *(uint2*)&p_s[w][l15 * 40 + 16 + 4 * g] = make_uint2(a2, a3);
      *(uint2*)&p_s[w][(16 + l15) * 40 + 4 * g] = make_uint2(b0, b1);
      *(uint2*)&p_s[w][(16 + l15) * 40 + 16 + 4 * g] = make_uint2(b2, b3);
    }
    bf16x8 ap0 = *(const bf16x8*)&p_s[w][l15 * 40 + g * 8];
    bf16x8 ap1 = *(const bf16x8*)&p_s[w][(16 + l15) * 40 + g * 8];
    bf16x8 bv0 = *(const bf16x8*)&vt_s[cur][(w * 32 + l15) * 40 + g * 8];
    bf16x8 bv1 = *(const bf16x8*)&vt_s[cur][(w * 32 + 16 + l15) * 40 + g * 8];
    o00 = MFMA_16x16x32(ap0, bv0, o00);
    o01 = MFMA_16x16x32(ap0, bv1, o01);
    o10 = MFMA_16x16x32(ap1, bv0, o10);
    o11 = MFMA_16x16x32(ap1, bv1, o11);

    if (kt < 15) WRITE_TILE(cur ^ 1);
    cur ^= 1;
  }
  if (lane < 16) { xch[w][l15] = l0; xch[w][16 + l15] = l1; }
  float4 la = *(const float4*)&xch[w][4 * g];
  float4 lb = *(const float4*)&xch[w][16 + 4 * g];
  size_t rowbase = (size_t)(b * TT + qt * 32);
#pragma unroll
  for (int r = 0; r < 4; r++) {
    int q0r = 4 * g + r;
    size_t base0 = (rowbase + q0r) * FD + w * 32 + l15;
    Ores[base0] = Q[base0] + o00[r] / la[r];
    Ores[base0 + 16] = Q[base0 + 16] + o01[r] / la[r];
    int q1r = 16 + 4 * g + r;
    size_t base1 = (rowbase + q1r) * FD + w * 32 + l15;
    Ores[base1] = Q[base1] + o10[r] / lb[r];
    Ores[base1 + 16] = Q[base1 + 16] + o11[r] / lb[r];
  }
#undef LOAD_TILE
#undef WRITE_TILE
}

// LN over 32-row fp32 tile (r10 wave-serial); wave w owns rows w*8..w*8+7.
__device__ __forceinline__ void ln32(float (*A)[132], short (*Xb)[136], int lane, int w,
                                     const float* __restrict__ gg,
                                     const float* __restrict__ bb,
                                     const float* mk, bool applyMask) {
  float ga = gg[lane], gb = gg[lane + 64], ba = bb[lane], b2 = bb[lane + 64];
  for (int j = 0; j < 8; j++) {
    int rr = w * 8 + j;
    float a = A[rr][lane], c = A[rr][lane + 64];
    float s = a + c, ss = a * a + c * c;
#pragma unroll
    for (int o = 32; o > 0; o >>= 1) { s += __shfl_xor(s, o); ss += __shfl_xor(ss, o); }
    float mean = s * (1.f / 128.f);
    float var = ss * (1.f / 128.f) - mean * mean;
    float rs = rsqrtf(var + 1e-5f);
    float m = applyMask ? mk[rr] : 1.f;
    float y0 = ((a - mean) * rs * ga + ba) * m;
    float y1 = ((c - mean) * rs * gb + b2) * m;
    A[rr][lane] = y0; A[rr][lane + 64] = y1;
    Xb[rr][lane] = f2b(y0); Xb[rr][lane + 64] = f2b(y1);
  }
}

// ---- post(layer1) + proj128(layer2), MFMA (r10) ----
__global__ __launch_bounds__(256) void post_proj_k(
    const float* __restrict__ Ores, const float* __restrict__ mask,
    const ushortt* __restrict__ wot, const float* __restrict__ bo,
    const float* __restrict__ g0, const float* __restrict__ be0,
    const float* __restrict__ g1, const float* __restrict__ be1,
    const ushortt* __restrict__ wqt, const float* __restrict__ bq,
    const ushortt* __restrict__ wkt, const float* __restrict__ bk,
    const ushortt* __restrict__ wvt, const float* __restrict__ bv,
    float* __restrict__ Q, ushortt* __restrict__ Kb, ushortt* __restrict__ Vt) {
  int base = blockIdx.x * 32;
  int b = base >> 9;
  int tloc = base & 511;
  int tid = threadIdx.x;
  int w = tid >> 6, lane = tid & 63;
  int l15 = lane & 15, g = lane >> 4;

  __shared__ float A32[32][132];
  __shared__ __align__(16) short Xb[32][136];
  __shared__ float mk[32];

  {
    int r = tid >> 3, c = (tid & 7) * 16;
    const float4* src = (const float4*)(Ores + (size_t)(base + r) * FD + c);
#pragma unroll
    for (int jj = 0; jj < 4; jj++) *(float4*)&A32[r][c + jj * 4] = src[jj];
  }
  if (tid < 32) mk[tid] = mask[base + tid];
  __syncthreads();
  ln32(A32, Xb, lane, w, g0, be0, mk, false);
  __syncthreads();

  int c0 = w * 32 + l15, c1 = c0 + 16;
  f32x4 f00 = {0.f, 0.f, 0.f, 0.f}, f01 = f00, f10 = f00, f11 = f00;
  GEMM128(wot, f00, f01, f10, f11);
  float bo0 = bo[c0], bo1 = bo[c1];
#pragma unroll
  for (int r = 0; r < 4; r++) {
    int r0 = g * 4 + r, r1 = 16 + r0;
    A32[r0][c0] += fmaxf(f00[r] + bo0, 0.f);
    A32[r0][c1] += fmaxf(f01[r] + bo1, 0.f);
    A32[r1][c0] += fmaxf(f10[r] + bo0, 0.f);
    A32[r1][c1] += fmaxf(f11[r] + bo1, 0.f);
  }
  __syncthreads();
  ln32(A32, Xb, lane, w, g1, be1, mk, true);
  __syncthreads();

  {
    f32x4 q00 = {0.f, 0.f, 0.f, 0.f}, q01 = q00, q10 = q00, q11 = q00;
    GEMM128(wqt, q00, q01, q10, q11);
    float bq0 = bq[c0], bq1 = bq[c1];
#pragma unroll
    for (int r = 0; r < 4; r++) {
      int r0 = g * 4 + r, r1 = 16 + r0;
      Q[(size_t)(base + r0) * FD + c0] = q00[r] + bq0;
      Q[(size_t)(base + r0) * FD + c1] = q01[r] + bq1;
      Q[(size_t)(base + r1) * FD + c0] = q10[r] + bq0;
      Q[(size_t)(base + r1) * FD + c1] = q11[r] + bq1;
    }
  }
  {
    f32x4 k00 = {0.f, 0.f, 0.f, 0.f}, k01 = k00, k10 = k00, k11 = k00;
    GEMM128(wkt, k00, k01, k10, k11);
    float bk0 = bk[c0], bk1 = bk[c1];
#pragma unroll
    for (int r = 0; r < 4; r++) {
      int r0 = g * 4 + r, r1 = 16 + r0;
      Kb[(size_t)(base + r0) * FD + c0] = (ushortt)f2b(k00[r] + bk0);
      Kb[(size_t)(base + r0) * FD + c1] = (ushortt)f2b(k01[r] + bk1);
      Kb[(size_t)(base + r1) * FD + c0] = (ushortt)f2b(k10[r] + bk0);
      Kb[(size_t)(base + r1) * FD + c1] = (ushortt)f2b(k11[r] + bk1);
    }
  }
  {
    f32x4 v00 = {0.f, 0.f, 0.f, 0.f}, v01 = v00, v10 = v00, v11 = v00;
    GEMM128(wvt, v00, v01, v10, v11);
    float bv0 = bv[c0], bv1 = bv[c1];
    short p[4];
#pragma unroll
    for (int k = 0; k < 4; k++) p[k] = f2b(v00[k] + bv0);
    *(s16x4*)&Vt[((size_t)b * FD + c0) * 512 + tloc + g * 4] = *(s16x4*)p;
#pragma unroll
    for (int k = 0; k < 4; k++) p[k] = f2b(v01[k] + bv1);
    *(s16x4*)&Vt[((size_t)b * FD + c1) * 512 + tloc + g * 4] = *(s16x4*)p;
#pragma unroll
    for (int k = 0; k < 4; k++) p[k] = f2b(v10[k] + bv0);
    *(s16x4*)&Vt[((size_t)b * FD + c0) * 512 + tloc + 16 + g * 4] = *(s16x4*)p;
#pragma unroll
    for (int k = 0; k < 4; k++) p[k] = f2b(v11[k] + bv1);
    *(s16x4*)&Vt[((size_t)b * FD + c1) * 512 + tloc + 16 + g * 4] = *(s16x4*)p;
  }
}

// ---- post(layer2) + ti + as-score, MFMA (r10 + race fix) ----
__global__ __launch_bounds__(256) void post_ti_k(
    const float* __restrict__ Ores, const float* __restrict__ mask,
    const ushortt* __restrict__ wot, const float* __restrict__ bo,
    const float* __restrict__ g0, const float* __restrict__ be0,
    const float* __restrict__ g1, const float* __restrict__ be1,
    const ushortt* __restrict__ wtit, const float* __restrict__ bti,
    const ushortt* __restrict__ wast, const float* __restrict__ bas,
    float* __restrict__ Xp2, float* __restrict__ S) {
  int base = blockIdx.x * 32;
  int tid = threadIdx.x;
  int w = tid >> 6, lane = tid & 63;
  int l15 = lane & 15, g = lane >> 4;

  __shared__ float A32[32][132];
  __shared__ __align__(16) short Xb[32][136];
  __shared__ float mk[32];

  {
    int r = tid >> 3, c = (tid & 7) * 16;
    const float4* src = (const float4*)(Ores + (size_t)(base + r) * FD + c);
#pragma unroll
    for (int jj = 0; jj < 4; jj++) *(float4*)&A32[r][c + jj * 4] = src[jj];
  }
  if (tid < 32) mk[tid] = mask[base + tid];
  __syncthreads();
  ln32(A32, Xb, lane, w, g0, be0, mk, false);
  __syncthreads();

  int c0 = w * 32 + l15, c1 = c0 + 16;
  f32x4 f00 = {0.f, 0.f, 0.f, 0.f}, f01 = f00, f10 = f00, f11 = f00;
  GEMM128(wot, f00, f01, f10, f11);
  float bo0 = bo[c0], bo1 = bo[c1];
#pragma unroll
  for (int r = 0; r < 4; r++) {
    int r0 = g * 4 + r, r1 = 16 + r0;
    A32[r0][c0] += fmaxf(f00[r] + bo0, 0.f);
    A32[r0][c1] += fmaxf(f01[r] + bo1, 0.f);
    A32[r1][c0] += fmaxf(f10[r] + bo0, 0.f);
    A32[r1][c1] += fmaxf(f11[r] + bo1, 0.f);
  }
  __syncthreads();
  ln32(A32, Xb, lane, w, g1, be1, mk, true);
  __syncthreads();

  // ti GEMM reads Xb (Xp); hold outputs in regs, write Xb only after barrier
  f32x4 t00 = {0.f, 0.f, 0.f, 0.f}, t01 = t00, t10 = t00, t11 = t00;
  GEMM128(wtit, t00, t01, t10, t11);
  float bti0 = bti[c0], bti1 = bti[c1];
  short pk[16];
#pragma unroll
  for (int r = 0; r < 4; r++) {
    int r0 = g * 4 + r, r1 = 16 + r0;
    float v00 = (t00[r] + bti0) * mk[r0];
    float v01 = (t01[r] + bti1) * mk[r0];
    float v10 = (t10[r] + bti0) * mk[r1];
    float v11 = (t11[r] + bti1) * mk[r1];
    Xp2[(size_t)(base + r0) * FD + c0] = v00;
    Xp2[(size_t)(base + r0) * FD + c1] = v01;
    Xp2[(size_t)(base + r1) * FD + c0] = v10;
    Xp2[(size_t)(base + r1) * FD + c1] = v11;
    pk[r * 4 + 0] = f2b(v00);
    pk[r * 4 + 1] = f2b(v01);
    pk[r * 4 + 2] = f2b(v10);
    pk[r * 4 + 3] = f2b(v11);
  }
  __syncthreads();  // RACE FIX: all waves' ti-GEMM Xb reads complete before overwrite
#pragma unroll
  for (int r = 0; r < 4; r++) {
    int r0 = g * 4 + r, r1 = 16 + r0;
    Xb[r0][c0] = pk[r * 4 + 0];
    Xb[r0][c1] = pk[r * 4 + 1];
    Xb[r1][c0] = pk[r * 4 + 2];
    Xb[r1][c1] = pk[r * 4 + 3];
  }
  __syncthreads();
  if (w < 2) {
    int a0 = w * 16 + l15;
    f32x4 s0 = {0.f, 0.f, 0.f, 0.f}, s1 = s0;
#pragma unroll
    for (int ks = 0; ks < 4; ks++) {
      bf16x8 aa0 = *(const bf16x8*)&Xb[l15][ks * 32 + g * 8];
      bf16x8 aa1 = *(const bf16x8*)&Xb[16 + l15][ks * 32 + g * 8];
      bf16x8 bb0 = *(const bf16x8*)(wast + (size_t)a0 * 128 + ks * 32 + g * 8);
      s0 = MFMA_16x16x32(aa0, bb0, s0);
      s1 = MFMA_16x16x32(aa1, bb0, s1);
    }
    float bas0 = bas[a0];
#pragma unroll
    for (int r = 0; r < 4; r++) {
      int r0 = g * 4 + r;
      S[(size_t)(base + r0) * NAGG + a0] = s0[r] + bas0;
      S[(size_t)(base + 16 + r0) * NAGG + a0] = s1[r] + bas0;
    }
  }
}

// ---- soft_t ----
__global__ void soft_t(const float* __restrict__ S, const float* __restrict__ mask,
                       float* __restrict__ att) {
  int b = blockIdx.x >> 5, a = blockIdx.x & 31;
  int tid = threadIdx.x;  // 128
  __shared__ float red[2];
  float sv[4], mv[4];
#pragma unroll
  for (int j = 0; j < 4; j++) {
    int t = tid + j * 128;
    sv[j] = S[(size_t)(b * TT + t) * NAGG + a];
    mv[j] = mask[b * TT + t];
  }
  float mx = fmaxf(fmaxf(sv[0], sv[1]), fmaxf(sv[2], sv[3]));
#pragma unroll
  for (int o = 32; o > 0; o >>= 1) mx = fmaxf(mx, __shfl_xor(mx, o));
  if ((tid & 63) == 0) red[tid >> 6] = mx;
  __syncthreads();
  mx = fmaxf(red[0], red[1]);
  __syncthreads();
  float e[4];
  float sm = 0.f;
#pragma unroll
  for (int j = 0; j < 4; j++) {
    e[j] = __expf(sv[j] - mx) * mv[j];
    sm += e[j];
  }
#pragma unroll
  for (int o = 32; o > 0; o >>= 1) sm += __shfl_xor(sm, o);
  if ((tid & 63) == 0) red[tid >> 6] = sm;
  __syncthreads();
  float inv = 1.f / (red[0] + red[1] + 1e-16f);
  float* dst = att + ((size_t)(b * NAGG + a)) * TT;
#pragma unroll
  for (int j = 0; j < 4; j++) dst[tid + j * 128] = e[j] * inv;
}

// ---- pool v2: block = (b, tc/4, fhalf, ag/2); Xp2 chunk staged ONCE, 16 a's/block ----
// partial layout: ((b*4 + tc)*32 + a)*128 + f
__global__ __launch_bounds__(256) void pool_k2(const float* __restrict__ Xp2,
                                               const float* __restrict__ att,
                                               const float* __restrict__ mask,
                                               float* __restrict__ pmax,
                                               float* __restrict__ pmin,
                                               float* __restrict__ psum) {
  int bid = blockIdx.x;
  int b = bid >> 4;
  int tc = (bid >> 2) & 3;
  int fg = (bid >> 1) & 1;
  int ag = bid & 1;
  int tid = threadIdx.x;
  __shared__ float xp_s[128][68];
  __shared__ float att_s[16][128];
  __shared__ float ms[128];
  {  // stage Xp2 chunk [128 t][64 f] fp32
    int r = tid >> 1, half = tid & 1;
    const float4* src =
        (const float4*)(Xp2 + ((size_t)(b * TT + tc * 128 + r)) * FD + fg * 64 + half * 32);
#pragma unroll
    for (int j = 0; j < 8; j++) *(float4*)&xp_s[r][half * 32 + j * 4] = src[j];
  }
  {  // stage att rows [16 a][128 t]
    int a = tid >> 4, t8 = (tid & 15) * 8;
    const float4* src =
        (const float4*)(att + ((size_t)(b * NAGG + ag * 16 + a)) * TT + tc * 128 + t8);
    *(float4*)&att_s[a][t8] = src[0];
    *(float4*)&att_s[a][t8 + 4] = src[1];
  }
  if (tid < 128) ms[tid] = mask[b * TT + tc * 128 + tid];
  __syncthreads();
  int fl = tid & 63, h = tid >> 6;  // h = wave = a-quad
  float mn[4], mx[4], sm[4];
#pragma unroll
  for (int a = 0; a < 4; a++) { mn[a] = 1e30f; mx[a] = -1e30f; sm[a] = 0.f; }
#pragma unroll 4
  for (int t = 0; t < 128; t++) {
    float e0 = xp_s[t][fl];
    bool keep = ms[t] > 0.f;
#pragma unroll
    for (int a = 0; a < 4; a++) {
      float e = e0 * att_s[h * 4 + a][t];
      mn[a] = fminf(mn[a], e);
      mx[a] = keep ? fmaxf(mx[a], e) : mx[a];
      sm[a] = keep ? sm[a] + e : sm[a];
    }
  }
#pragma unroll
  for (int a = 0; a < 4; a++) {
    int aa = ag * 16 + h * 4 + a;
    size_t idx = ((size_t)((b * 4 + tc) * 32 + aa)) * 128 + fg * 64 + fl;
    pmax[idx] = mx[a];
    pmin[idx] = mn[a];
    psum[idx] = sm[a];
  }
}

// ---- combine (pool_k2 partial indexing) ----
__global__ void combine_k(const float* __restrict__ pmax, const float* __restrict__ pmin,
                          const float* __restrict__ psum, const float* __restrict__ mask,
                          float* __restrict__ aggF, float* __restrict__ agg_out) {
  int b = blockIdx.x >> 5, a = blockIdx.x & 31;
  int f = threadIdx.x;
  __shared__ float red[2];
  float ntp = 0.f;
#pragma unroll
  for (int j = 0; j < 4; j++) ntp += (mask[b * TT + f + j * 128] > 0.f) ? 1.f : 0.f;
#pragma unroll
  for (int o = 32; o > 0; o >>= 1) ntp += __shfl_xor(ntp, o);
  if ((f & 63) == 0) red[f >> 6] = ntp;
  __syncthreads();
  float nt = red[0] + red[1];
  float mx = -1e30f, mn = 1e30f, sm = 0.f;
#pragma unroll
  for (int tc = 0; tc < 4; tc++) {
    size_t idx = ((size_t)((b * 4 + tc) * 32 + a)) * 128 + f;
    mx = fmaxf(mx, pmax[idx]);
    mn = fminf(mn, pmin[idx]);
    sm += psum[idx];
  }
  bool anyUn = nt < 511.5f;
  float mp = anyUn ? fmaxf(mx, mn - 1.f) : mx;
  float mean = sm / (nt == 0.f ? 1.f : nt);
  size_t bs = (size_t)b * 8192 + (size_t)a * 256;
  aggF[bs + f] = mp;
  aggF[bs + 128 + f] = mean;
  agg_out[bs + f] = mp;
  agg_out[bs + 128 + f] = mean;
}

// ---- aggmm ----
__global__ void aggmm_k(const float* __restrict__ aggF, const float* __restrict__ wto,
                        float* __restrict__ part) {
  int b = blockIdx.x >> 5, cc = blockIdx.x & 31;
  int f = threadIdx.x;
  __shared__ float ag[256];
  ag[f] = aggF[(size_t)b * 8192 + cc * 256 + f];
  ag[128 + f] = aggF[(size_t)b * 8192 + cc * 256 + 128 + f];
  __syncthreads();
  const float* w = wto + ((size_t)(IND + FD) + cc * 256) * FD;
  float a0 = 0.f, a1 = 0.f, a2 = 0.f, a3 = 0.f;
#pragma unroll 4
  for (int j = 0; j < 256; j += 4) {
    a0 += ag[j] * w[(size_t)j * FD + f];
    a1 += ag[j + 1] * w[(size_t)(j + 1) * FD + f];
    a2 += ag[j + 2] * w[(size_t)(j + 2) * FD + f];
    a3 += ag[j + 3] * w[(size_t)(j + 3) * FD + f];
  }
  part[(size_t)(b * 32 + cc) * FD + f] = (a0 + a1) + (a2 + a3);
}

// ---- final, MFMA (r10 wave-serial LN tail) ----
__global__ __launch_bounds__(256) void final_k(
    const float* __restrict__ X, const float* __restrict__ Xp2,
    const float* __restrict__ part, const ushortt* __restrict__ wtot,
    const float* __restrict__ wto, const float* __restrict__ bto,
    const float* __restrict__ gto, const float* __restrict__ btoln,
    const float* __restrict__ mask, float* __restrict__ out) {
  int base = blockIdx.x * 32;
  int b = base >> 9;
  int tid = threadIdx.x;
  int w = tid >> 6, lane = tid & 63;
  int l15 = lane & 15, g = lane >> 4;
  __shared__ float A32[32][132];
  __shared__ __align__(16) short Xb[32][136];
  __shared__ float xss[32][17];
  __shared__ float psum_s[128];
  __shared__ float mk[32];
  {
    int r = tid >> 3, c = (tid & 7) * 16;
    const float4* src = (const float4*)(Xp2 + (size_t)(base + r) * FD + c);
#pragma unroll
    for (int jj = 0; jj < 4; jj++) {
      float4 v = src[jj];
      *(s16x4*)&Xb[r][c + jj * 4] = (s16x4){f2b(v.x), f2b(v.y), f2b(v.z), f2b(v.w)};
    }
  }
  {
    int r = tid >> 3, ii = (tid & 7) * 2;
    xss[r][ii] = X[(size_t)(base + r) * IND + ii];
    xss[r][ii + 1] = X[(size_t)(base + r) * IND + ii + 1];
  }
  if (tid < 32) mk[tid] = mask[base + tid];
  if (tid < 128) {
    float ps = 0.f;
#pragma unroll 8
    for (int cc = 0; cc < 32; cc++) ps += part[(size_t)(b * 32 + cc) * FD + tid];
    psum_s[tid] = ps;
  }
  __syncthreads();
  int c0 = w * 32 + l15, c1 = c0 + 16;
  f32x4 q00 = {0.f, 0.f, 0.f, 0.f}, q01 = q00, q10 = q00, q11 = q00;
  GEMM128(wtot, q00, q01, q10, q11);
  float wx0[16], wx1[16];
#pragma unroll
  for (int i = 0; i < 16; i++) { wx0[i] = wto[i * FD + c0]; wx1[i] = wto[i * FD + c1]; }
  float add0 = bto[c0] + psum_s[c0], add1 = bto[c1] + psum_s[c1];
#pragma unroll
  for (int r = 0; r < 4; r++) {
    int r0 = g * 4 + r, r1 = 16 + r0;
    float x00 = q00[r] + add0, x01 = q01[r] + add1;
    float x10 = q10[r] + add0, x11 = q11[r] + add1;
#pragma unroll
    for (int i = 0; i < 16; i++) {
      x00 += xss[r0][i] * wx0[i];
      x01 += xss[r0][i] * wx1[i];
      x10 += xss[r1][i] * wx0[i];
      x11 += xss[r1][i] * wx1[i];
    }
    A32[r0][c0] = x00; A32[r0][c1] = x01;
    A32[r1][c0] = x10; A32[r1][c1] = x11;
  }
  __syncthreads();
  float ga = gto[lane], gb = gto[lane + 64], ba = btoln[lane], bb2 = btoln[lane + 64];
  for (int j = 0; j < 8; j++) {
    int rr = w * 8 + j;
    float a = A32[rr][lane], c = A32[rr][lane + 64];
    float s = a + c, ss = a * a + c * c;
#pragma unroll
    for (int o = 32; o > 0; o >>= 1) { s += __shfl_xor(s, o); ss += __shfl_xor(ss, o); }
    float mean = s * (1.f / 128.f);
    float var = ss * (1.f / 128.f) - mean * mean;
    float rs = rsqrtf(var + 1e-5f);
    float m = mk[rr];
    out[(size_t)(base + rr) * FD + lane] = fmaxf((a - mean) * rs * ga + ba, 0.f) * m;
    out[(size_t)(base + rr) * FD + lane + 64] = fmaxf((c - mean) * rs * gb + bb2, 0.f) * m;
  }
}

extern "C" void kernel_launch(void* const* d_in, const int* in_sizes, int n_in,
                              void* d_out, int out_size, void* d_ws, size_t ws_size,
                              hipStream_t stream) {
  const float* X    = (const float*)d_in[0];
  const float* mask = (const float*)d_in[1];
  const float* wq0 = (const float*)d_in[2];  const float* bq0 = (const float*)d_in[3];
  const float* wk0 = (const float*)d_in[4];  const float* bk0 = (const float*)d_in[5];
  const float* wv0 = (const float*)d_in[6];  const float* bv0 = (const float*)d_in[7];
  const float* wo0 = (const float*)d_in[8];  const float* bo0 = (const float*)d_in[9];
  const float* g00 = (const float*)d_in[10]; const float* be00 = (const float*)d_in[11];
  const float* g10 = (const float*)d_in[12]; const float* be10 = (const float*)d_in[13];
  const float* wq1 = (const float*)d_in[14]; const float* bq1 = (const float*)d_in[15];
  const float* wk1 = (const float*)d_in[16]; const float* bk1 = (const float*)d_in[17];
  const float* wv1 = (const float*)d_in[18]; const float* bv1 = (const float*)d_in[19];
  const float* wo1 = (const float*)d_in[20]; const float* bo1 = (const float*)d_in[21];
  const float* g01 = (const float*)d_in[22]; const float* be01 = (const float*)d_in[23];
  const float* g11 = (const float*)d_in[24]; const float* be11 = (const float*)d_in[25];
  const float* wti = (const float*)d_in[26]; const float* bti = (const float*)d_in[27];
  const float* was = (const float*)d_in[28]; const float* bas = (const float*)d_in[29];
  const float* wto = (const float*)d_in[30]; const float* bto = (const float*)d_in[31];
  const float* gto = (const float*)d_in[32]; const float* btoln = (const float*)d_in[33];

  const size_t BIG = (size_t)BB * TT * FD;  // 2,097,152 floats
  float* ws = (float*)d_ws;
  float* Qf = ws;
  ushortt* Kb = (ushortt*)(ws + BIG);
  ushortt* Vt = (ushortt*)(ws + BIG + BIG / 2);
  float* Ores = Qf;
  float* Xp2 = ws + BIG;
  float* S    = ws + 2 * BIG;
  float* att  = ws + 2 * BIG + 524288;
  float* aggF = ws + 2 * BIG + 1048576;
  float* part = ws + 2 * BIG + 1310720;
  ushortt* Wt = (ushortt*)(ws + 2 * BIG + 1441792);  // 8 x 16384 bf16
  float* pmax = ws;                                  // dead Qf/Ores region
  float* pmin = ws + 524288;
  float* psum = ws + 1048576;

  ushortt* wo0t = Wt;
  ushortt* wq1t = Wt + 16384;
  ushortt* wk1t = Wt + 2 * 16384;
  ushortt* wv1t = Wt + 3 * 16384;
  ushortt* wo1t = Wt + 4 * 16384;
  ushortt* wtit = Wt + 5 * 16384;
  ushortt* wtot = Wt + 6 * 16384;
  ushortt* wast = Wt + 7 * 16384;

  float* out_main = (float*)d_out;
  float* out_agg  = (float*)d_out + BIG;

  int nrb = BB * TT / 8;    // 2048
  int nrb32 = BB * TT / 32; // 512
  prep_w_k<<<32, 256, 0, stream>>>(wo0, wq1, wk1, wv1, wo1, wti, wto, was, Wt);
  proj16_k<<<nrb, 128, 0, stream>>>(X, wq0, bq0, wk0, bk0, wv0, bv0, Qf, Kb, Vt);
  attn_k<<<BB * 16, 256, 0, stream>>>(Qf, Kb, Vt, mask, Ores);
  post_proj_k<<<nrb32, 256, 0, stream>>>(Ores, mask, wo0t, bo0, g00, be00, g10, be10,
                                         wq1t, bq1, wk1t, bk1, wv1t, bv1, Qf, Kb, Vt);
  attn_k<<<BB * 16, 256, 0, stream>>>(Qf, Kb, Vt, mask, Ores);
  post_ti_k<<<nrb32, 256, 0, stream>>>(Ores, mask, wo1t, bo1, g01, be01, g11, be11,
                                       wtit, bti, wast, bas, Xp2, S);
  soft_t<<<BB * NAGG, 128, 0, stream>>>(S, mask, att);
  pool_k2<<<BB * 16, 256, 0, stream>>>(Xp2, att, mask, pmax, pmin, psum);
  combine_k<<<BB * NAGG, 128, 0, stream>>>(pmax, pmin, psum, mask, aggF, out_agg);
  aggmm_k<<<BB * 32, 128, 0, stream>>>(aggF, wto, part);
  final_k<<<nrb32, 256, 0, stream>>>(X, Xp2, part, wtot, wto, bto, gto, btoln, mask, out_main);
}